// Round 15
// baseline (46.377 us; speedup 1.0000x reference)
//
#include <hip/hip_runtime.h>
#include <hip/hip_bf16.h>
#include <cstdint>
#include <cstddef>

// Problem constants
#define Bsz 16384
#define Esz 16
#define Ssz 64
#define Asz 32
#define Isz 96   // S + A
#define HSz 64
#define HRz 32

#define PT 512        // prep threads
#define NTM 256       // main threads (4 waves)
#define CHUNK 512     // state-block rows
#define NTILE 8       // CHUNK / (4 waves * 16 rows)
#define NSB 512       // state blocks
#define RCHUNK 2048   // reward-block rows
#define RNTILE 32
#define NRB 128       // reward blocks

typedef __attribute__((ext_vector_type(8))) short bf16x8;
typedef __attribute__((ext_vector_type(4))) short short4v;
typedef __attribute__((ext_vector_type(4))) float f32x4;

static __device__ __forceinline__ short f2bf(float f) {
    __hip_bfloat16 b = __float2bfloat16(f);   // pairs into v_cvt_pk_bf16_f32
    return *reinterpret_cast<short*>(&b);
}
static __device__ __forceinline__ float bf2f(short s) {
    union { uint32_t u; float f; } v; v.u = ((uint32_t)(uint16_t)s) << 16; return v.f;
}

// ---- Prep: X = concat(state,action) -> bf16 row-major [B][96] ----
__global__ void prep_x(const float* __restrict__ state, const float* __restrict__ action,
                       short* __restrict__ Xbf) {
    int idx = blockIdx.x * blockDim.x + threadIdx.x;   // [0, Bsz*96/8)
    int g = idx * 8;
    int row = g / Isz, rem = g - row * Isz;            // rem multiple of 8
    float4 lo, hi;
    if (rem < Ssz) {
        const float* p = state + (size_t)row * Ssz + rem;
        lo = *(const float4*)(p); hi = *(const float4*)(p + 4);
    } else {
        const float* p = action + (size_t)row * Asz + (rem - Ssz);
        lo = *(const float4*)(p); hi = *(const float4*)(p + 4);
    }
    bf16x8 r;
    r[0] = f2bf(lo.x); r[1] = f2bf(lo.y); r[2] = f2bf(lo.z); r[3] = f2bf(lo.w);
    r[4] = f2bf(hi.x); r[5] = f2bf(hi.y); r[6] = f2bf(hi.z); r[7] = f2bf(hi.w);
    *(bf16x8*)&Xbf[(size_t)row * Isz + rem] = r;
}

// Main: blocks [0,NSB) = state MLP (lean, target <=168 VGPR -> 3 waves/SIMD);
// blocks [NSB,NSB+NRB) = reward MLP (light). 640 blocks <= 768 slots at 3/CU.
// Swapped mfma(Wfrag, Xfrag): D lane: m = lane&15, n = nt*16 + (lane>>4)*4 + j.
__global__ __launch_bounds__(NTM, 3)
void fused_main(const short* __restrict__ Xbf,
                const float* __restrict__ W1, const float* __restrict__ b1,
                const float* __restrict__ W2, const float* __restrict__ b2,
                const float* __restrict__ rW1, const float* __restrict__ rb1,
                const float* __restrict__ rW2, const float* __restrict__ rb2,
                float* __restrict__ outS, float* __restrict__ outR)
{
    // Per-wave H buffer [m=16][h=64], row stride 68 shorts: ~2-way max. 8704 B.
    __shared__ __align__(16) short HT[4][16][68];

    const int bid = blockIdx.x;
    const int w = threadIdx.x >> 6, lane = threadIdx.x & 63;
    const int lr = lane & 15, lg = lane >> 4;

    if (bid < NSB) {
        // ================= STATE PATH =================
        const int xcd = bid & 7;
        const int rem = bid >> 3;
        const int e   = rem & (Esz - 1);
        const int c0  = (xcd + 8 * (rem >> 4)) * CHUNK;

        // Weight fragments: per-lane gather from f32 (proven in R12), convert once.
        // Fragment (nt,kk): lane holds W[k=kk*32+lg*8+t][n=nt*16+lr], t=0..7.
        bf16x8 w1r[4][3], w2r[4][2];
        {
            const float* base = W1 + (size_t)e * Isz * HSz;
            #pragma unroll
            for (int nt = 0; nt < 4; ++nt)
                #pragma unroll
                for (int kk = 0; kk < 3; ++kk) {
                    const float* p = base + (kk * 32 + lg * 8) * HSz + nt * 16 + lr;
                    bf16x8 r;
                    #pragma unroll
                    for (int t = 0; t < 8; ++t) r[t] = f2bf(p[t * HSz]);
                    w1r[nt][kk] = r;
                }
        }
        {
            const float* base = W2 + (size_t)e * HSz * Ssz;
            #pragma unroll
            for (int nt = 0; nt < 4; ++nt)
                #pragma unroll
                for (int kk = 0; kk < 2; ++kk) {
                    const float* p = base + (kk * 32 + lg * 8) * Ssz + nt * 16 + lr;
                    bf16x8 r;
                    #pragma unroll
                    for (int t = 0; t < 8; ++t) r[t] = f2bf(p[t * Ssz]);
                    w2r[nt][kk] = r;
                }
        }
        // Biases packed bf16 (lane's D slots: n = nt*16 + lg*4 + j)
        short4v b1p[4], b2p[4];
        #pragma unroll
        for (int nt = 0; nt < 4; ++nt) {
            float4 v1 = *(const float4*)&b1[e * HSz + nt * 16 + lg * 4];
            float4 v2 = *(const float4*)&b2[e * Ssz + nt * 16 + lg * 4];
            b1p[nt] = (short4v){ f2bf(v1.x), f2bf(v1.y), f2bf(v1.z), f2bf(v1.w) };
            b2p[nt] = (short4v){ f2bf(v2.x), f2bf(v2.y), f2bf(v2.z), f2bf(v2.w) };
        }

        const int row0 = c0 + w * 16 + lr;           // lane's base batch row (m = lr)
        const short* xbase = Xbf + (size_t)row0 * Isz + lg * 8;

        // bf16 A-fragments direct (no cvt), 1-tile rotating prefetch
        bf16x8 a0 = *(const bf16x8*)(xbase);
        bf16x8 a1 = *(const bf16x8*)(xbase + 32);
        bf16x8 a2 = *(const bf16x8*)(xbase + 64);

        #pragma unroll 1
        for (int t = 0; t < NTILE; ++t) {
            const int tn = (t + 1) & (NTILE - 1);    // wrap: last iter re-reads t=0 (discarded)
            const short* xn = xbase + (size_t)tn * 64 * Isz;
            bf16x8 n0 = *(const bf16x8*)(xn);
            bf16x8 n1 = *(const bf16x8*)(xn + 32);
            bf16x8 n2 = *(const bf16x8*)(xn + 64);

            // Layer 1: acc initialized with bias
            f32x4 accS[4];
            #pragma unroll
            for (int nt = 0; nt < 4; ++nt) {
                f32x4 acc = (f32x4){ bf2f(b1p[nt][0]), bf2f(b1p[nt][1]),
                                     bf2f(b1p[nt][2]), bf2f(b1p[nt][3]) };
                acc = __builtin_amdgcn_mfma_f32_16x16x32_bf16(w1r[nt][0], a0, acc, 0, 0, 0);
                acc = __builtin_amdgcn_mfma_f32_16x16x32_bf16(w1r[nt][1], a1, acc, 0, 0, 0);
                acc = __builtin_amdgcn_mfma_f32_16x16x32_bf16(w1r[nt][2], a2, acc, 0, 0, 0);
                accS[nt] = acc;
            }
            // H = relu(accS) -> HT (lane holds 4 consecutive h of row lr)
            #pragma unroll
            for (int nt = 0; nt < 4; ++nt) {
                short4v p = { f2bf(fmaxf(accS[nt][0], 0.f)),
                              f2bf(fmaxf(accS[nt][1], 0.f)),
                              f2bf(fmaxf(accS[nt][2], 0.f)),
                              f2bf(fmaxf(accS[nt][3], 0.f)) };
                *(short4v*)&HT[w][lr][nt * 16 + lg * 4] = p;
            }
            // Layer 2: H frags via b128 (wave-private, in-order DS)
            bf16x8 h0 = *(const bf16x8*)&HT[w][lr][lg * 8];
            bf16x8 h1 = *(const bf16x8*)&HT[w][lr][32 + lg * 8];
            #pragma unroll
            for (int nt = 0; nt < 4; ++nt) {
                f32x4 acc = (f32x4){ bf2f(b2p[nt][0]), bf2f(b2p[nt][1]),
                                     bf2f(b2p[nt][2]), bf2f(b2p[nt][3]) };
                acc = __builtin_amdgcn_mfma_f32_16x16x32_bf16(w2r[nt][0], h0, acc, 0, 0, 0);
                acc = __builtin_amdgcn_mfma_f32_16x16x32_bf16(w2r[nt][1], h1, acc, 0, 0, 0);
                __builtin_nontemporal_store(acc,
                    (f32x4*)&outS[((size_t)e * Bsz + row0 + t * 64) * Ssz + nt * 16 + lg * 4]);
            }
            a0 = n0; a1 = n1; a2 = n2;
        }
    } else {
        // ================= REWARD PATH =================
        const int rbid = bid - NSB;
        const int e  = rbid & (Esz - 1);
        const int c0 = (rbid >> 4) * RCHUNK;

        bf16x8 rw1r[2][3];
        {
            const float* base = rW1 + (size_t)e * Isz * HRz;
            #pragma unroll
            for (int nt = 0; nt < 2; ++nt)
                #pragma unroll
                for (int kk = 0; kk < 3; ++kk) {
                    const float* p = base + (kk * 32 + lg * 8) * HRz + nt * 16 + lr;
                    bf16x8 r;
                    #pragma unroll
                    for (int t = 0; t < 8; ++t) r[t] = f2bf(p[t * HRz]);
                    rw1r[nt][kk] = r;
                }
        }
        short4v rb1p[2], rw2p[2];
        #pragma unroll
        for (int nt = 0; nt < 2; ++nt) {
            float4 v1 = *(const float4*)&rb1[e * HRz + nt * 16 + lg * 4];
            float4 v2 = *(const float4*)&rW2[e * HRz + nt * 16 + lg * 4];
            rb1p[nt] = (short4v){ f2bf(v1.x), f2bf(v1.y), f2bf(v1.z), f2bf(v1.w) };
            rw2p[nt] = (short4v){ f2bf(v2.x), f2bf(v2.y), f2bf(v2.z), f2bf(v2.w) };
        }
        const float rb2s = rb2[e];

        const int row0 = c0 + w * 16 + lr;
        const short* xbase = Xbf + (size_t)row0 * Isz + lg * 8;

        bf16x8 a0 = *(const bf16x8*)(xbase);
        bf16x8 a1 = *(const bf16x8*)(xbase + 32);
        bf16x8 a2 = *(const bf16x8*)(xbase + 64);

        #pragma unroll 1
        for (int t = 0; t < RNTILE; ++t) {
            const int tn = (t + 1) & (RNTILE - 1);
            const short* xn = xbase + (size_t)tn * 64 * Isz;
            bf16x8 n0 = *(const bf16x8*)(xn);
            bf16x8 n1 = *(const bf16x8*)(xn + 32);
            bf16x8 n2 = *(const bf16x8*)(xn + 64);

            f32x4 accR[2];
            #pragma unroll
            for (int nt = 0; nt < 2; ++nt) {
                f32x4 acc = (f32x4){ bf2f(rb1p[nt][0]), bf2f(rb1p[nt][1]),
                                     bf2f(rb1p[nt][2]), bf2f(rb1p[nt][3]) };
                acc = __builtin_amdgcn_mfma_f32_16x16x32_bf16(rw1r[nt][0], a0, acc, 0, 0, 0);
                acc = __builtin_amdgcn_mfma_f32_16x16x32_bf16(rw1r[nt][1], a1, acc, 0, 0, 0);
                acc = __builtin_amdgcn_mfma_f32_16x16x32_bf16(rw1r[nt][2], a2, acc, 0, 0, 0);
                accR[nt] = acc;
            }
            float rp = 0.f;
            #pragma unroll
            for (int nt = 0; nt < 2; ++nt) {
                rp += fmaxf(accR[nt][0], 0.f) * bf2f(rw2p[nt][0]);
                rp += fmaxf(accR[nt][1], 0.f) * bf2f(rw2p[nt][1]);
                rp += fmaxf(accR[nt][2], 0.f) * bf2f(rw2p[nt][2]);
                rp += fmaxf(accR[nt][3], 0.f) * bf2f(rw2p[nt][3]);
            }
            rp += __shfl_xor(rp, 16);
            rp += __shfl_xor(rp, 32);
            if (lane < 16)
                __builtin_nontemporal_store(fminf(fmaxf(rp + rb2s, -100.f), 200.f),
                                            &outR[(size_t)e * Bsz + row0 + t * 64]);
            a0 = n0; a1 = n1; a2 = n2;
        }
    }
}

extern "C" void kernel_launch(void* const* d_in, const int* in_sizes, int n_in,
                              void* d_out, int out_size, void* d_ws, size_t ws_size,
                              hipStream_t stream) {
    const float* state  = (const float*)d_in[0];
    const float* action = (const float*)d_in[1];
    const float* W1  = (const float*)d_in[2];
    const float* b1  = (const float*)d_in[3];
    const float* W2  = (const float*)d_in[4];
    const float* b2  = (const float*)d_in[5];
    const float* rW1 = (const float*)d_in[6];
    const float* rb1 = (const float*)d_in[7];
    const float* rW2 = (const float*)d_in[8];
    const float* rb2 = (const float*)d_in[9];

    float* outS = (float*)d_out;                      // [E, B, S]
    float* outR = outS + (size_t)Esz * Bsz * Ssz;     // [E, B, 1]

    short* Xbf = (short*)d_ws;                        // Bsz*Isz bf16 (3.1 MB)

    prep_x<<<(Bsz * Isz / 8) / PT, PT, 0, stream>>>(state, action, Xbf);  // 384 blocks
    fused_main<<<NSB + NRB, NTM, 0, stream>>>(                            // 640 blocks
        Xbf, W1, b1, W2, b2, rW1, rb1, rW2, rb2, outS, outR);
}

// Round 16
// 25.606 us; speedup vs baseline: 1.8112x; 1.8112x over previous
//
#include <hip/hip_runtime.h>
#include <hip/hip_bf16.h>
#include <cstdint>
#include <cstddef>

// Problem constants
#define Bsz 16384
#define Esz 16
#define Ssz 64
#define Asz 32
#define Isz 96   // S + A
#define HSz 64
#define HRz 32

#define NTM 256       // 4 waves
#define CHUNK 512     // batch rows per block
#define NTILE 8       // CHUNK / (4 waves * 16 rows)

typedef __attribute__((ext_vector_type(8))) short bf16x8;
typedef __attribute__((ext_vector_type(4))) short short4v;
typedef __attribute__((ext_vector_type(4))) float f32x4;

static __device__ __forceinline__ short f2bf(float f) {
    __hip_bfloat16 b = __float2bfloat16(f);   // pairs into v_cvt_pk_bf16_f32
    return *reinterpret_cast<short*>(&b);
}
static __device__ __forceinline__ float bf2f(short s) {
    union { uint32_t u; float f; } v; v.u = ((uint32_t)(uint16_t)s) << 16; return v.f;
}
static __device__ __forceinline__ bf16x8 pack8(float4 lo, float4 hi) {
    bf16x8 r;
    r[0] = f2bf(lo.x); r[1] = f2bf(lo.y); r[2] = f2bf(lo.z); r[3] = f2bf(lo.w);
    r[4] = f2bf(hi.x); r[5] = f2bf(hi.y); r[6] = f2bf(hi.z); r[7] = f2bf(hi.w);
    return r;
}

// R12 (best, 27.3 us) + FULL-LINE COALESCED OUTPUT STORES.
// Layer-2 f32 results route through a per-wave LDS tile; each wave then writes
// its 4 KB outS region (16 consecutive batch rows x 256 B, contiguous) as four
// 1 KB fully-contiguous nt-stores -> no 64 B partial-line writes, no HBM RMW.
// Everything else identical to R12 (weights-in-VGPR, swapped MFMA, XCD swizzle).
__global__ __launch_bounds__(NTM, 2)
void fused_all(const float* __restrict__ state, const float* __restrict__ action,
               const float* __restrict__ W1, const float* __restrict__ b1,
               const float* __restrict__ W2, const float* __restrict__ b2,
               const float* __restrict__ rW1, const float* __restrict__ rb1,
               const float* __restrict__ rW2, const float* __restrict__ rb2,
               float* __restrict__ outS, float* __restrict__ outR)
{
    // HT: per-wave H transpose, stride 68 shorts (136 B) -> ~2-way banks. 8704 B.
    __shared__ __align__(16) short HT[4][16][68];
    // OT: per-wave f32 output staging [m=16][s=64], stride 72 floats (288 B,
    // 16B-mult). Write ~2-way, read ~4-way banks (one-off per tile). 18432 B.
    __shared__ __align__(16) float OT[4][16][72];
    // total LDS 27136 B -> 2 blocks/CU unchanged

    // ---- XCD-aware sibling swizzle (bijective over 512 blocks) ----
    const int bid = blockIdx.x;
    const int xcd = bid & 7;
    const int rem = bid >> 3;
    const int e   = rem & (Esz - 1);
    const int c0  = (xcd + 8 * (rem >> 4)) * CHUNK;

    const int w = threadIdx.x >> 6, lane = threadIdx.x & 63;
    const int lr = lane & 15, lg = lane >> 4;

    // ---- Weight fragments: per-lane gather from f32, convert once ----
    // Fragment (nt,kk): lane holds W[k = kk*32 + lg*8 + t][n = nt*16 + lr], t=0..7.
    bf16x8 w1r[4][3], rw1r[2][3], w2r[4][2];
    {
        const float* base = W1 + (size_t)e * Isz * HSz;
        #pragma unroll
        for (int nt = 0; nt < 4; ++nt)
            #pragma unroll
            for (int kk = 0; kk < 3; ++kk) {
                const float* p = base + (kk * 32 + lg * 8) * HSz + nt * 16 + lr;
                bf16x8 r;
                #pragma unroll
                for (int t = 0; t < 8; ++t) r[t] = f2bf(p[t * HSz]);
                w1r[nt][kk] = r;
            }
    }
    {
        const float* base = rW1 + (size_t)e * Isz * HRz;
        #pragma unroll
        for (int nt = 0; nt < 2; ++nt)
            #pragma unroll
            for (int kk = 0; kk < 3; ++kk) {
                const float* p = base + (kk * 32 + lg * 8) * HRz + nt * 16 + lr;
                bf16x8 r;
                #pragma unroll
                for (int t = 0; t < 8; ++t) r[t] = f2bf(p[t * HRz]);
                rw1r[nt][kk] = r;
            }
    }
    {
        const float* base = W2 + (size_t)e * HSz * Ssz;
        #pragma unroll
        for (int nt = 0; nt < 4; ++nt)
            #pragma unroll
            for (int kk = 0; kk < 2; ++kk) {
                const float* p = base + (kk * 32 + lg * 8) * Ssz + nt * 16 + lr;
                bf16x8 r;
                #pragma unroll
                for (int t = 0; t < 8; ++t) r[t] = f2bf(p[t * Ssz]);
                w2r[nt][kk] = r;
            }
    }

    // ---- Biases packed bf16 (lane's D slots: n = nt*16 + lg*4 + j) ----
    short4v b1p[4], b2p[4], rb1p[2], rw2p[2];
    #pragma unroll
    for (int nt = 0; nt < 4; ++nt) {
        float4 v1 = *(const float4*)&b1[e * HSz + nt * 16 + lg * 4];
        float4 v2 = *(const float4*)&b2[e * Ssz + nt * 16 + lg * 4];
        b1p[nt] = (short4v){ f2bf(v1.x), f2bf(v1.y), f2bf(v1.z), f2bf(v1.w) };
        b2p[nt] = (short4v){ f2bf(v2.x), f2bf(v2.y), f2bf(v2.z), f2bf(v2.w) };
    }
    #pragma unroll
    for (int nt = 0; nt < 2; ++nt) {
        float4 v1 = *(const float4*)&rb1[e * HRz + nt * 16 + lg * 4];
        float4 v2 = *(const float4*)&rW2[e * HRz + nt * 16 + lg * 4];
        rb1p[nt] = (short4v){ f2bf(v1.x), f2bf(v1.y), f2bf(v1.z), f2bf(v1.w) };
        rw2p[nt] = (short4v){ f2bf(v2.x), f2bf(v2.y), f2bf(v2.z), f2bf(v2.w) };
    }
    const float rb2s = rb2[e];

    // ---- X pipeline: f32 loads (prefetched) -> cvt_pk -> bf16 fragments ----
    const int row0 = c0 + w * 16 + lr;               // this lane's base batch row (m = lr)
    const float* sbase = state  + (size_t)row0 * Ssz + lg * 8;
    const float* abase = action + (size_t)row0 * Asz + lg * 8;

    float4 xs0 = *(const float4*)(sbase);
    float4 xs1 = *(const float4*)(sbase + 4);
    float4 xs2 = *(const float4*)(sbase + 32);
    float4 xs3 = *(const float4*)(sbase + 36);
    float4 xa0 = *(const float4*)(abase);
    float4 xa1 = *(const float4*)(abase + 4);
    bf16x8 a0 = pack8(xs0, xs1);
    bf16x8 a1 = pack8(xs2, xs3);
    bf16x8 a2 = pack8(xa0, xa1);

    #pragma unroll 1
    for (int t = 0; t < NTILE; ++t) {
        // Prefetch next tile's f32 rows (wraps on last iter; L2-hit, discarded)
        const int tn = (t + 1) & (NTILE - 1);
        const float* sp = sbase + (size_t)tn * 64 * Ssz;
        const float* ap = abase + (size_t)tn * 64 * Asz;
        float4 ns0 = *(const float4*)(sp);
        float4 ns1 = *(const float4*)(sp + 4);
        float4 ns2 = *(const float4*)(sp + 32);
        float4 ns3 = *(const float4*)(sp + 36);
        float4 na0 = *(const float4*)(ap);
        float4 na1 = *(const float4*)(ap + 4);

        // ---- Layer 1 (state): acc initialized with bias (free add) ----
        f32x4 accS[4];
        #pragma unroll
        for (int nt = 0; nt < 4; ++nt) {
            f32x4 acc = (f32x4){ bf2f(b1p[nt][0]), bf2f(b1p[nt][1]),
                                 bf2f(b1p[nt][2]), bf2f(b1p[nt][3]) };
            acc = __builtin_amdgcn_mfma_f32_16x16x32_bf16(w1r[nt][0], a0, acc, 0, 0, 0);
            acc = __builtin_amdgcn_mfma_f32_16x16x32_bf16(w1r[nt][1], a1, acc, 0, 0, 0);
            acc = __builtin_amdgcn_mfma_f32_16x16x32_bf16(w1r[nt][2], a2, acc, 0, 0, 0);
            accS[nt] = acc;
        }
        // ---- Layer 1 (reward) ----
        f32x4 accR[2];
        #pragma unroll
        for (int nt = 0; nt < 2; ++nt) {
            f32x4 acc = (f32x4){ bf2f(rb1p[nt][0]), bf2f(rb1p[nt][1]),
                                 bf2f(rb1p[nt][2]), bf2f(rb1p[nt][3]) };
            acc = __builtin_amdgcn_mfma_f32_16x16x32_bf16(rw1r[nt][0], a0, acc, 0, 0, 0);
            acc = __builtin_amdgcn_mfma_f32_16x16x32_bf16(rw1r[nt][1], a1, acc, 0, 0, 0);
            acc = __builtin_amdgcn_mfma_f32_16x16x32_bf16(rw1r[nt][2], a2, acc, 0, 0, 0);
            accR[nt] = acc;
        }

        // ---- H = relu(accS) -> HT (lane holds 4 consecutive h of row lr) ----
        #pragma unroll
        for (int nt = 0; nt < 4; ++nt) {
            short4v p = { f2bf(fmaxf(accS[nt][0], 0.f)),
                          f2bf(fmaxf(accS[nt][1], 0.f)),
                          f2bf(fmaxf(accS[nt][2], 0.f)),
                          f2bf(fmaxf(accS[nt][3], 0.f)) };
            *(short4v*)&HT[w][lr][nt * 16 + lg * 4] = p;
        }

        // ---- Reward layer 2 in registers ----
        float rp = 0.f;
        #pragma unroll
        for (int nt = 0; nt < 2; ++nt) {
            rp += fmaxf(accR[nt][0], 0.f) * bf2f(rw2p[nt][0]);
            rp += fmaxf(accR[nt][1], 0.f) * bf2f(rw2p[nt][1]);
            rp += fmaxf(accR[nt][2], 0.f) * bf2f(rw2p[nt][2]);
            rp += fmaxf(accR[nt][3], 0.f) * bf2f(rw2p[nt][3]);
        }
        rp += __shfl_xor(rp, 16);
        rp += __shfl_xor(rp, 32);
        if (lane < 16)
            __builtin_nontemporal_store(fminf(fmaxf(rp + rb2s, -100.f), 200.f),
                                        &outR[(size_t)e * Bsz + row0 + t * 64]);

        // ---- Layer 2 (state): H frags via b128; results -> OT (wave-private) ----
        bf16x8 h0 = *(const bf16x8*)&HT[w][lr][lg * 8];
        bf16x8 h1 = *(const bf16x8*)&HT[w][lr][32 + lg * 8];
        #pragma unroll
        for (int nt = 0; nt < 4; ++nt) {
            f32x4 acc = (f32x4){ bf2f(b2p[nt][0]), bf2f(b2p[nt][1]),
                                 bf2f(b2p[nt][2]), bf2f(b2p[nt][3]) };
            acc = __builtin_amdgcn_mfma_f32_16x16x32_bf16(w2r[nt][0], h0, acc, 0, 0, 0);
            acc = __builtin_amdgcn_mfma_f32_16x16x32_bf16(w2r[nt][1], h1, acc, 0, 0, 0);
            *(f32x4*)&OT[w][lr][nt * 16 + lg * 4] = acc;   // D slot: row lr, col nt*16+lg*4
        }
        // ---- Full-line coalesced stores: wave's 4 KB region (16 rows x 256 B,
        //      contiguous in outS) as 4 x 1KB nt-stores (64 lanes x 16 B) ----
        {
            const size_t obase = ((size_t)e * Bsz + c0 + t * 64 + w * 16) * Ssz;
            #pragma unroll
            for (int q = 0; q < 4; ++q) {
                // float index q*256 + lane*4  ->  row 4q + (lane>>4), col (lane&15)*4
                f32x4 v = *(const f32x4*)&OT[w][4 * q + (lane >> 4)][(lane & 15) * 4];
                __builtin_nontemporal_store(v, (f32x4*)&outS[obase + q * 256 + lane * 4]);
            }
        }

        // ---- Convert prefetched f32 -> current fragments (vmcnt wait lands here) ----
        a0 = pack8(ns0, ns1);
        a1 = pack8(ns2, ns3);
        a2 = pack8(na0, na1);
    }
}

extern "C" void kernel_launch(void* const* d_in, const int* in_sizes, int n_in,
                              void* d_out, int out_size, void* d_ws, size_t ws_size,
                              hipStream_t stream) {
    const float* state  = (const float*)d_in[0];
    const float* action = (const float*)d_in[1];
    const float* W1  = (const float*)d_in[2];
    const float* b1  = (const float*)d_in[3];
    const float* W2  = (const float*)d_in[4];
    const float* b2  = (const float*)d_in[5];
    const float* rW1 = (const float*)d_in[6];
    const float* rb1 = (const float*)d_in[7];
    const float* rW2 = (const float*)d_in[8];
    const float* rb2 = (const float*)d_in[9];

    float* outS = (float*)d_out;                      // [E, B, S]
    float* outR = outS + (size_t)Esz * Bsz * Ssz;     // [E, B, 1]

    fused_all<<<Esz * (Bsz / CHUNK), NTM, 0, stream>>>(   // 512 blocks, 1 generation
        state, action, W1, b1, W2, b2, rW1, rb1, rW2, rb2, outS, outR);
}